// Round 9
// baseline (12.229 us; speedup 1.0000x reference)
//
#include <hip/hip_runtime.h>
#include <math.h>

// Problem constants (B=256, N=32, D=D1=128, R=O=8)
#define NPAIR 64
#define NCENTER 2048
#define WCAP 48
#define RSLOT 32

typedef __attribute__((ext_vector_type(8))) short bfrag8;
typedef __attribute__((ext_vector_type(8))) unsigned short u16x8;
typedef __attribute__((ext_vector_type(4))) float f32x4;

__device__ __forceinline__ float gelu_f(float v) {
    return 0.5f * v * (1.0f + erff(v * 0.70710678118654752f));
}
__device__ __forceinline__ unsigned short f2bf(float f) {   // RNE fp32->bf16
    unsigned int u = __float_as_uint(f);
    return (unsigned short)((u + 0x7FFFu + ((u >> 16) & 1u)) >> 16);
}

// ONE dispatch, 2048 blocks = 64 pairs x 4 col-quarters x 8 slices.
// pair = blk & 63 -> all 32 blocks of a pair on one XCD (blk%8 == pair%8):
// M fetched from HBM once per pair (4 MB), re-read from that XCD's L2.
// Per block: convert its pair's QUARTER-matrix (32 cols x 128 d) fp32->bf16
// transposed into LDS [c][d] (4-bit XOR swizzle, conflict-free b128 R+W);
// ballot-bin its slice's rows (deterministic, proven R4-R8); per 32-row
// chunk stage x bf16 and run mfma_f32_16x16x32_bf16, wave = (rt, ct).
// 17.3 KB LDS + 64-VGPR budget -> 8 blocks/CU (32 waves/CU, max occupancy);
// 2048 blocks = exactly one resident set.
__global__ __launch_bounds__(256, 8) void fused_kernel(
    const float* __restrict__ center_h,
    const float* __restrict__ raw_neighbors,
    const float* __restrict__ Mg,
    const float* __restrict__ bias,
    const int* __restrict__ center_o,
    const int* __restrict__ s_types,
    const int* __restrict__ o_types,
    float* __restrict__ out)
{
    __shared__ __align__(16) unsigned short Mbt[32 * 128];   // 8KB [c_loc][d]
    __shared__ __align__(16) unsigned short Xs[RSLOT * 128]; // 8KB [slot][d]
    __shared__ int list[4 * WCAP];
    __shared__ int cnts[4];
    __shared__ int rowid[RSLOT];

    const int t    = threadIdx.x;
    const int wave = t >> 6, lane = t & 63;
    const int pair = blockIdx.x & 63;
    const int rest = blockIdx.x >> 6;        // 0..31
    const int q    = rest & 3;               // col-quarter
    const int slice = rest >> 2;             // 0..7
    const int r0 = pair >> 3, o0 = pair & 7;

    // --- scan loads first
    const int4 svv = ((const int4*)s_types)[slice * 256 + t];
    const int4 ovv = ((const int4*)o_types)[slice * 256 + t];
    const int my_b  = slice * 32 + wave * 8 + (lane & 7);
    const int my_co = center_o[my_b];

    // --- M quarter-matrix loads: thread (dblk=t>>4, lane16=t&15) reads cols
    // c_loc = 16*i + lane16 (i<2), d = dblk*8+r (r<8). 16 dwords/thread;
    // per (i,r) instr a 16-lane cluster reads 64B contiguous.
    const int lane16 = t & 15, dblk = t >> 4;
    float g[2][8];
    {
        const float* mp = Mg + pair * 16384 + (dblk * 8) * 128 + q * 32;
        #pragma unroll
        for (int i = 0; i < 2; ++i)
            #pragma unroll
            for (int r = 0; r < 8; ++r)
                g[i][r] = mp[r * 128 + 16 * i + lane16];
    }

    // --- ballot compaction (deterministic; proven R4-R8 verbatim)
    int cw = 0;
    {
        const bool match = (lane < 8) && (my_co == o0);
        const unsigned long long mk = __ballot(match);
        const int pre = __builtin_amdgcn_mbcnt_hi(
            (unsigned)(mk >> 32), __builtin_amdgcn_mbcnt_lo((unsigned)mk, 0));
        if (match) {
            const int pos = cw + pre;
            if (pos < WCAP) list[wave * WCAP + pos] = my_b * 8 + r0;
        }
        cw += __popcll(mk);
    }
    {
        const int ss[4] = { svv.x, svv.y, svv.z, svv.w };
        const int oo[4] = { ovv.x, ovv.y, ovv.z, ovv.w };
        const int base_nid = slice * 1024 + t * 4;
        #pragma unroll
        for (int j = 0; j < 4; ++j) {
            const int s = ss[j] < 0 ? 0 : ss[j];
            const int o = oo[j] < 0 ? 0 : oo[j];
            const bool match = (s == r0) & (o == o0);
            const unsigned long long mk = __ballot(match);
            const int pre = __builtin_amdgcn_mbcnt_hi(
                (unsigned)(mk >> 32), __builtin_amdgcn_mbcnt_lo((unsigned)mk, 0));
            if (match) {
                const int pos = cw + pre;
                if (pos < WCAP) list[wave * WCAP + pos] = NCENTER + base_nid + j;
            }
            cw += __popcll(mk);
            if (cw > WCAP) cw = WCAP;
        }
    }
    if (lane == 0) cnts[wave] = cw;

    // --- pack + transposed swizzled write of M quarter into LDS
    // granule dch at col c holds d = dch*8+j; g_idx = dblk ^ (c&15);
    // per instr c&15 = lane16 -> 16 distinct granule slots: conflict-free.
    #pragma unroll
    for (int i = 0; i < 2; ++i) {
        const int c = 16 * i + lane16;
        u16x8 w;
        #pragma unroll
        for (int r = 0; r < 8; ++r) w[r] = f2bf(g[i][r]);
        *(u16x8*)((char*)Mbt + c * 256 + ((dblk ^ lane16) << 4)) = w;
    }
    __syncthreads();   // Mbt + lists + cnts visible

    const int c0_ = cnts[0], c1_ = cnts[1], c2_ = cnts[2];
    const int cnt = c0_ + c1_ + c2_ + cnts[3];

    const int lo16 = lane & 15, hi4 = lane >> 4;
    const int ct = wave & 1, rt = wave >> 1;     // wave -> (col-tile, row-tile)
    const int c_loc = ct * 16 + lo16;            // local col 0..31
    const int colg  = q * 32 + c_loc;            // global col
    const float bv = bias[pair * 128 + colg];

    for (int base = 0; base < cnt; base += RSLOT) {
        const int csz = (cnt - base < RSLOT) ? (cnt - base) : RSLOT;

        if (t < RSLOT) {
            int id = -1;
            int a = base + t;
            if (a < cnt) {
                int sw = 0;
                if (a >= c0_) { a -= c0_; sw = 1;
                    if (a >= c1_) { a -= c1_; sw = 2;
                        if (a >= c2_) { a -= c2_; sw = 3; } } }
                id = list[sw * WCAP + a];
            }
            rowid[t] = id;
        }
        __syncthreads();   // rowid visible

        // stage x rows (bf16, swizzled g = chg ^ (slot&15)); pad rows zero.
        #pragma unroll
        for (int i = 0; i < 2; ++i) {
            const int flat = i * 256 + t;          // 32 slots x 16 granules
            const int slot = flat >> 4, chg = flat & 15;
            const int id = rowid[slot];
            u16x8 w = {0, 0, 0, 0, 0, 0, 0, 0};
            if (id >= 0) {
                const float* xp = (id < NCENTER) ? center_h + (id >> 3) * 128
                                                 : raw_neighbors + (id - NCENTER) * 128;
                const float4 x0 = *(const float4*)(xp + chg * 8);
                const float4 x1 = *(const float4*)(xp + chg * 8 + 4);
                w[0] = f2bf(x0.x); w[1] = f2bf(x0.y); w[2] = f2bf(x0.z); w[3] = f2bf(x0.w);
                w[4] = f2bf(x1.x); w[5] = f2bf(x1.y); w[6] = f2bf(x1.z); w[7] = f2bf(x1.w);
            }
            *(u16x8*)((char*)Xs + slot * 256 + ((chg ^ (slot & 15)) << 4)) = w;
        }
        __syncthreads();   // Xs visible

        // MFMA: wave handles row-tile rt (slots rt*16..+15), col-tile ct.
        // A row = lo16 (+rt*16), k = hi4*8+j -> granule dch = 4k+hi4;
        // row&15 == lo16 == c_loc&15 -> shared swizzle offset gsl.
        f32x4 acc = {bv, bv, bv, bv};
        #pragma unroll
        for (int k = 0; k < 4; ++k) {
            const int dch = 4 * k + hi4;
            const int gsl = (dch ^ lo16) << 4;
            const bfrag8 a = *(const bfrag8*)((const char*)Xs  + (rt * 16 + lo16) * 256 + gsl);
            const bfrag8 b = *(const bfrag8*)((const char*)Mbt + c_loc * 256 + gsl);
            acc = __builtin_amdgcn_mfma_f32_16x16x32_bf16(a, b, acc, 0, 0, 0);
        }

        // epilogue: D col = lane&15 (-> colg), row-in-tile = hi4*4 + j
        #pragma unroll
        for (int j = 0; j < 4; ++j) {
            const int s = rt * 16 + hi4 * 4 + j;
            if (s < csz) out[rowid[s] * 128 + colg] = gelu_f(acc[j]);
        }
        __syncthreads();   // protect Xs/rowid before next chunk
    }
}

extern "C" void kernel_launch(void* const* d_in, const int* in_sizes, int n_in,
                              void* d_out, int out_size, void* d_ws, size_t ws_size,
                              hipStream_t stream) {
    const float* center_h      = (const float*)d_in[0];
    const float* raw_neighbors = (const float*)d_in[1];
    const float* M             = (const float*)d_in[2];
    const float* bias          = (const float*)d_in[3];
    const int*   center_o      = (const int*)d_in[4];
    const int*   s_types       = (const int*)d_in[5];
    const int*   o_types       = (const int*)d_in[6];
    float* out = (float*)d_out;

    fused_kernel<<<dim3(NPAIR * 32), dim3(256), 0, stream>>>(
        center_h, raw_neighbors, M, bias, center_o, s_types, o_types, out);
}